// Round 27
// baseline (119.243 us; speedup 1.0000x reference)
//
#include <hip/hip_runtime.h>
#include <cstdint>
#include <cstddef>

#define B_TOT   16384
#define F_DIM   1024
#define P_TOT   1024
#define K_IN    9
#define W_H     10
#define TB      64      // batch rows per block (1 per lane)
#define THREADS 1024    // 16 waves
#define NWAVE   16
#define PGRP    2       // patch groups (P split across blocks)
#define PPB     (P_TOT / PGRP)   // 512 patches per block
#define LSTR    1028    // LDS x row stride in BYTES (fp8); conflict-free gathers
#define XS_BYTES (TB * LSTR)     // 65792

// record, REC_DW=64 dwords (= 64 lanes x 1 dword -> one coalesced load):
//   [0..8]=idx  [9]=s1*C  [10..19]=b1*C
//   [20]=c0  [21..30]=cw (f32)  [31]=pad
//   [32..54]=W1q (45 fp8-pairs)  [55..63]=pad
#define REC_DW   64
#define TANH_C   2.8853900817779268f    // 2*log2(e)
#define F8_MAX   448.0f                 // e4m3fn max finite

typedef float f32x2 __attribute__((ext_vector_type(2)));

__device__ __forceinline__ float fast_exp2(float x) {
#if __has_builtin(__builtin_amdgcn_exp2f)
    return __builtin_amdgcn_exp2f(x);
#else
    return exp2f(x);
#endif
}
__device__ __forceinline__ float fast_rcp(float x) {
#if __has_builtin(__builtin_amdgcn_rcpf)
    return __builtin_amdgcn_rcpf(x);
#else
    return 1.0f / x;
#endif
}
// r = 1/(exp2(z)+1), z = 2*log2e*(Wx+b); tanh = 1-2r folded into cw,c0
__device__ __forceinline__ float sigm_r(float z) {
    return fast_rcp(fast_exp2(z) + 1.0f);
}
__device__ __forceinline__ f32x2 pkfma(f32x2 a, f32x2 b, f32x2 c) {
#if __has_builtin(__builtin_elementwise_fma)
    return __builtin_elementwise_fma(a, b, c);   // -> v_pk_fma_f32
#else
    return f32x2{fmaf(a[0], b[0], c[0]), fmaf(a[1], b[1], c[1])};
#endif
}
// unpack fp8 pair from halfword 0 / 1 of dword u (constant selectors only)
__device__ __forceinline__ f32x2 unpk8_w0(uint32_t u) {
#if __has_builtin(__builtin_amdgcn_cvt_pk_f32_fp8)
    auto v = __builtin_amdgcn_cvt_pk_f32_fp8((int)u, false);
    return f32x2{v[0], v[1]};
#else
    return f32x2{__builtin_amdgcn_cvt_f32_fp8((int)u, 0),
                 __builtin_amdgcn_cvt_f32_fp8((int)u, 1)};
#endif
}
__device__ __forceinline__ f32x2 unpk8_w1(uint32_t u) {
#if __has_builtin(__builtin_amdgcn_cvt_pk_f32_fp8)
    auto v = __builtin_amdgcn_cvt_pk_f32_fp8((int)u, true);
    return f32x2{v[0], v[1]};
#else
    return f32x2{__builtin_amdgcn_cvt_f32_fp8((int)u, 2),
                 __builtin_amdgcn_cvt_f32_fp8((int)u, 3)};
#endif
}
__device__ __forceinline__ f32x2 unpk8s(uint32_t u, int word) {
    return word ? unpk8_w1(u) : unpk8_w0(u);
}
// pack two fp32 pairs -> one dword of 4 fp8 (constant word args)
__device__ __forceinline__ uint32_t pk2(float a0, float a1, float b0, float b1) {
    uint32_t u = (uint32_t)__builtin_amdgcn_cvt_pk_fp8_f32(a0, a1, 0, false);
    u = (uint32_t)__builtin_amdgcn_cvt_pk_fp8_f32(b0, b1, (int)u, true);
    return u;
}

// ---- prep: one value for record dword dw of patch p ----
__device__ __forceinline__ uint32_t rec_dword(
    int p, int dw, const int* idx,
    const float* w1, const float* b1, const float* w2, const float* b2,
    const float* w3, const float* b3, const float* wl,
    float s1, float q1)
{
    if (dw < 9)  return (uint32_t)idx[p * 9 + dw];
    if (dw == 9) return __float_as_uint(s1 * TANH_C);
    if (dw < 20) return __float_as_uint(b1[p * 10 + (dw - 10)] * TANH_C);
    if (dw == 20) {                    // c0 = wl*(sum_w W23[w] + sum_v b2[v]w3[v] + b3)
        float bb = b3[p];
        for (int v = 0; v < 10; ++v) bb = fmaf(b2[p * 10 + v], w3[v], bb);
        float s = 0.f;
        for (int w = 0; w < 10; ++w)
            for (int v = 0; v < 10; ++v)
                s = fmaf(w2[w * 10 + v], w3[v], s);
        return __float_as_uint(wl[p] * (s + bb));
    }
    if (dw < 31) {                     // cw[w] = -2*wl*sum_v W2[w][v]*W3[v]
        const int w = dw - 21;
        float s = 0.f;
        for (int v = 0; v < 10; ++v) s = fmaf(w2[w * 10 + v], w3[v], s);
        return __float_as_uint(-2.0f * wl[p] * s);
    }
    if (dw < 32) return 0;
    if (dw < 55) {                     // W1q: pair t -> e=(t/5)*10+2*(t%5)
        const int d = dw - 32, t0 = 2 * d, t1 = t0 + 1;
        const int e0 = (t0 / 5) * 10 + 2 * (t0 % 5);
        const float a0 = w1[e0] * q1, a1 = w1[e0 + 1] * q1;
        float bq0 = 0.f, bq1 = 0.f;
        if (t1 < 45) {
            const int e1 = (t1 / 5) * 10 + 2 * (t1 % 5);
            bq0 = w1[e1] * q1; bq1 = w1[e1 + 1] * q1;
        }
        return pk2(a0, a1, bq0, bq1);
    }
    return 0;
}

// ---- prep: build records, 1 WAVE per patch ----
__global__ __launch_bounds__(64)
void prep_quant(const int* __restrict__ idx,
                const float* __restrict__ W1, const float* __restrict__ b1,
                const float* __restrict__ W2, const float* __restrict__ b2,
                const float* __restrict__ W3, const float* __restrict__ b3,
                const float* __restrict__ wl, uint32_t* __restrict__ ws)
{
    const int p = blockIdx.x;
    const int l = threadIdx.x;           // 0..63
    const float* w1 = W1 + p * 90;
    const float* w2 = W2 + p * 100;
    const float* w3 = W3 + p * 10;

    // wave-parallel amax over W1 (order-independent -> deterministic scale)
    float m1 = (l < 90) ? fabsf(w1[l]) : 0.0f;
    if (l + 64 < 90) m1 = fmaxf(m1, fabsf(w1[l + 64]));
    #pragma unroll
    for (int off = 32; off > 0; off >>= 1)
        m1 = fmaxf(m1, __shfl_xor(m1, off));
    m1 = fmaxf(m1, 1e-20f);
    const float s1 = m1 / F8_MAX, q1 = F8_MAX / m1;

    ws[(size_t)p * REC_DW + l] =
        rec_dword(p, l, idx, w1, b1, w2, b2, w3, b3, wl, s1, q1);
}

__global__ __launch_bounds__(THREADS, 8)   // 8 waves/SIMD -> 2 blocks/CU
void dnn_q8(const float* __restrict__ x, const uint32_t* __restrict__ ws,
            const float* __restrict__ wl, float* __restrict__ out)
{
    extern __shared__ unsigned char xs[];   // x tile + record slots
    __shared__ float partial[NWAVE][TB];    // 4 KB

    const int tid = threadIdx.x;
    const int b0  = blockIdx.x * TB;
    const int p0  = blockIdx.y * PPB;

    // ---- stage x tile (fp32 global, coalesced float4) -> fp8 LDS ----
    #pragma unroll
    for (int i = 0; i < (TB * (F_DIM / 4)) / THREADS; ++i) {   // 16 iters
        const int q   = i * THREADS + tid;
        const int row = q >> 8;
        const int c4  = q & 255;
        const float4 v = *reinterpret_cast<const float4*>(
            x + (size_t)(b0 + row) * F_DIM + (c4 << 2));
        int pk = __builtin_amdgcn_cvt_pk_fp8_f32(v.x, v.y, 0, false);
        pk     = __builtin_amdgcn_cvt_pk_fp8_f32(v.z, v.w, pk, true);
        *reinterpret_cast<uint32_t*>(xs + row * LSTR + (c4 << 2)) = (uint32_t)pk;
    }
    __syncthreads();

    const int lane = tid & 63;           // lane = local batch row
    const int wave = tid >> 6;
    const unsigned char* __restrict__ myrow = xs + lane * LSTR;
    // wave-private double-buffered record slots: [NWAVE][2][64] dwords
    uint32_t* slots = reinterpret_cast<uint32_t*>(xs + XS_BYTES) + wave * (2 * REC_DW);

    float yacc = 0.0f;

    // prologue: stage first record into slot 0 (T14: global -> reg -> LDS)
    slots[lane] = ws[(size_t)(p0 + wave) * REC_DW + lane];
    int cur = 0;

    for (int jp = 0; jp < PPB / NWAVE; ++jp) {   // 32 iters, 1 patch/wave, 1 row/lane
        const int p = p0 + jp * NWAVE + wave;
        const uint32_t* __restrict__ rec = slots + cur * REC_DW;  // wave-uniform LDS addr
        const float*    __restrict__ rf  = reinterpret_cast<const float*>(rec);

        // T14 issue-early: next record's 256B coalesced load (1 dword/lane);
        // matching ds_write lands after ~900cy of compute -> latency hidden.
        // Tail reads past record 1023 stay inside ws (>=950KB) - unused.
        const uint32_t stg = ws[(size_t)(p + NWAVE) * REC_DW + lane];

        // gather 9 features (conflict-free: stride 1028 B, uniform column)
        float xg[K_IN];
        #pragma unroll
        for (int k = 0; k < K_IN; ++k)
            xg[k] = __builtin_amdgcn_cvt_f32_fp8((int)myrow[(int)rec[k]], 0);

        // layer 1: quantized accumulate (W1q via broadcast ds_reads)
        f32x2 H[5];
        #pragma unroll
        for (int j = 0; j < 5; ++j) H[j] = f32x2{0.f, 0.f};
        #pragma unroll
        for (int k = 0; k < K_IN; ++k) {
            const f32x2 xk = {xg[k], xg[k]};
            #pragma unroll
            for (int j = 0; j < 5; ++j) {
                const int t = k * 5 + j;
                H[j] = pkfma(xk, unpk8s(rec[32 + (t >> 1)], t & 1), H[j]);
            }
        }
        // z = H*s1C + b1C; r = 1/(exp2(z)+1)  (tanh = 1-2r folded into cw,c0)
        const float s1c = rf[9];
        const f32x2 s1p = {s1c, s1c};
        f32x2 r[5];
        #pragma unroll
        for (int j = 0; j < 5; ++j) {
            const f32x2 bj = {rf[10 + 2 * j], rf[11 + 2 * j]};
            const f32x2 z = pkfma(H[j], s1p, bj);
            r[j] = f32x2{sigm_r(z[0]), sigm_r(z[1])};
        }

        // collapsed layers 2+3: y += c0 + sum_w cw[w]*r_w
        const float c0 = rf[20];
        f32x2 A = {0.f, 0.f};
        #pragma unroll
        for (int j = 0; j < 5; ++j) {
            const f32x2 cwj = {rf[21 + 2 * j], rf[22 + 2 * j]};
            A = pkfma(cwj, r[j], A);
        }
        yacc += c0 + A[0] + A[1];

        // T14 write-late: park the prefetched record for the next iteration
        slots[(cur ^ 1) * REC_DW + lane] = stg;
        cur ^= 1;
    }

    partial[wave][lane] = yacc;
    __syncthreads();

    // ---- block reduction over the 16 waves + outputs ----
    if (tid < TB) {
        float s = 0.0f;
        #pragma unroll
        for (int w = 0; w < NWAVE; ++w) s += partial[w][tid];
        // two pgroup blocks contribute per y element; fp32 add is commutative
        atomicAdd(&out[b0 + tid], s);

        if (blockIdx.y == 0) {
            // channel 2: sum(|w_last|), computed redundantly per row-block
            float sa = 0.0f;
            #pragma unroll
            for (int i = 0; i < P_TOT / TB; ++i) sa += fabsf(wl[tid + TB * i]);
            #pragma unroll
            for (int off = 32; off > 0; off >>= 1) sa += __shfl_down(sa, off);
            sa = __shfl(sa, 0);
            out[B_TOT + b0 + tid] = sa;   // single writer
        }
    }
}

extern "C" void kernel_launch(void* const* d_in, const int* in_sizes, int n_in,
                              void* d_out, int out_size, void* d_ws, size_t ws_size,
                              hipStream_t stream)
{
    const float* x  = (const float*)d_in[0];
    const int*   idx= (const int*)  d_in[1];
    const float* W1 = (const float*)d_in[2];
    const float* b1 = (const float*)d_in[3];
    const float* W2 = (const float*)d_in[4];
    const float* b2 = (const float*)d_in[5];
    const float* W3 = (const float*)d_in[6];
    const float* b3 = (const float*)d_in[7];
    const float* wl = (const float*)d_in[8];
    float* out = (float*)d_out;
    uint32_t* ws = (uint32_t*)d_ws;   // need 256KB + tail pad; ws >= 950KB (R10)

    // zero the y channel (atomicAdd accumulates into it)
    (void)hipMemsetAsync(out, 0, B_TOT * sizeof(float), stream);

    prep_quant<<<P_TOT, 64, 0, stream>>>(idx, W1, b1, W2, b2, W3, b3, wl, ws);

    const int smem = XS_BYTES + NWAVE * 2 * REC_DW * 4;  // 65792 + 8192 = 73984 B
    (void)hipFuncSetAttribute(reinterpret_cast<const void*>(dnn_q8),
                              hipFuncAttributeMaxDynamicSharedMemorySize, smem);

    dim3 grid(B_TOT / TB, PGRP);   // 256 x 2 = 512 blocks -> 2 blocks/CU
    dnn_q8<<<grid, THREADS, smem, stream>>>(x, ws, wl, out);
}

// Round 28
// 104.804 us; speedup vs baseline: 1.1378x; 1.1378x over previous
//
#include <hip/hip_runtime.h>
#include <cstdint>
#include <cstddef>

#define B_TOT   16384
#define F_DIM   1024
#define P_TOT   1024
#define K_IN    9
#define W_H     10
#define TB      128     // batch rows per block (2 per lane)
#define THREADS 1024    // 16 waves
#define NWAVE   16
#define PGRP    2       // patch groups (P split across blocks)
#define PPB     (P_TOT / PGRP)   // 512 patches per block
#define LSTR    1028    // LDS x row stride in BYTES (fp8); conflict-free gathers
#define XS_BYTES (TB * LSTR)     // 131584

// record, REC_DW=64 dwords (= 64 lanes x 1 dword -> one coalesced load):
//   [0..8]=idx  [9]=s1*C  [10..19]=b1*C
//   [20]=c0  [21..30]=cw (f32)  [31]=pad
//   [32..54]=W1q (45 fp8-pairs)  [55..63]=pad
#define REC_DW   64
#define TANH_C   2.8853900817779268f    // 2*log2(e)
#define F8_MAX   448.0f                 // e4m3fn max finite

typedef float f32x2 __attribute__((ext_vector_type(2)));

__device__ __forceinline__ float fast_exp2(float x) {
#if __has_builtin(__builtin_amdgcn_exp2f)
    return __builtin_amdgcn_exp2f(x);
#else
    return exp2f(x);
#endif
}
__device__ __forceinline__ float fast_rcp(float x) {
#if __has_builtin(__builtin_amdgcn_rcpf)
    return __builtin_amdgcn_rcpf(x);
#else
    return 1.0f / x;
#endif
}
// r = 1/(exp2(z)+1), z = 2*log2e*(Wx+b); tanh = 1-2r folded into cw,c0
__device__ __forceinline__ float sigm_r(float z) {
    return fast_rcp(fast_exp2(z) + 1.0f);
}
__device__ __forceinline__ f32x2 pkfma(f32x2 a, f32x2 b, f32x2 c) {
#if __has_builtin(__builtin_elementwise_fma)
    return __builtin_elementwise_fma(a, b, c);   // -> v_pk_fma_f32
#else
    return f32x2{fmaf(a[0], b[0], c[0]), fmaf(a[1], b[1], c[1])};
#endif
}
// unpack fp8 pair from halfword 0 / 1 of dword u (constant selectors only)
__device__ __forceinline__ f32x2 unpk8_w0(uint32_t u) {
#if __has_builtin(__builtin_amdgcn_cvt_pk_f32_fp8)
    auto v = __builtin_amdgcn_cvt_pk_f32_fp8((int)u, false);
    return f32x2{v[0], v[1]};
#else
    return f32x2{__builtin_amdgcn_cvt_f32_fp8((int)u, 0),
                 __builtin_amdgcn_cvt_f32_fp8((int)u, 1)};
#endif
}
__device__ __forceinline__ f32x2 unpk8_w1(uint32_t u) {
#if __has_builtin(__builtin_amdgcn_cvt_pk_f32_fp8)
    auto v = __builtin_amdgcn_cvt_pk_f32_fp8((int)u, true);
    return f32x2{v[0], v[1]};
#else
    return f32x2{__builtin_amdgcn_cvt_f32_fp8((int)u, 2),
                 __builtin_amdgcn_cvt_f32_fp8((int)u, 3)};
#endif
}
__device__ __forceinline__ f32x2 unpk8s(uint32_t u, int word) {
    return word ? unpk8_w1(u) : unpk8_w0(u);
}
// pack two fp32 pairs -> one dword of 4 fp8 (constant word args)
__device__ __forceinline__ uint32_t pk2(float a0, float a1, float b0, float b1) {
    uint32_t u = (uint32_t)__builtin_amdgcn_cvt_pk_fp8_f32(a0, a1, 0, false);
    u = (uint32_t)__builtin_amdgcn_cvt_pk_fp8_f32(b0, b1, (int)u, true);
    return u;
}

// ---- prep: one value for record dword dw of patch p ----
__device__ __forceinline__ uint32_t rec_dword(
    int p, int dw, const int* idx,
    const float* w1, const float* b1, const float* w2, const float* b2,
    const float* w3, const float* b3, const float* wl,
    float s1, float q1)
{
    if (dw < 9)  return (uint32_t)idx[p * 9 + dw];
    if (dw == 9) return __float_as_uint(s1 * TANH_C);
    if (dw < 20) return __float_as_uint(b1[p * 10 + (dw - 10)] * TANH_C);
    if (dw == 20) {                    // c0 = wl*(sum_w W23[w] + sum_v b2[v]w3[v] + b3)
        float bb = b3[p];
        for (int v = 0; v < 10; ++v) bb = fmaf(b2[p * 10 + v], w3[v], bb);
        float s = 0.f;
        for (int w = 0; w < 10; ++w)
            for (int v = 0; v < 10; ++v)
                s = fmaf(w2[w * 10 + v], w3[v], s);
        return __float_as_uint(wl[p] * (s + bb));
    }
    if (dw < 31) {                     // cw[w] = -2*wl*sum_v W2[w][v]*W3[v]
        const int w = dw - 21;
        float s = 0.f;
        for (int v = 0; v < 10; ++v) s = fmaf(w2[w * 10 + v], w3[v], s);
        return __float_as_uint(-2.0f * wl[p] * s);
    }
    if (dw < 32) return 0;
    if (dw < 55) {                     // W1q: pair t -> e=(t/5)*10+2*(t%5)
        const int d = dw - 32, t0 = 2 * d, t1 = t0 + 1;
        const int e0 = (t0 / 5) * 10 + 2 * (t0 % 5);
        const float a0 = w1[e0] * q1, a1 = w1[e0 + 1] * q1;
        float bq0 = 0.f, bq1 = 0.f;
        if (t1 < 45) {
            const int e1 = (t1 / 5) * 10 + 2 * (t1 % 5);
            bq0 = w1[e1] * q1; bq1 = w1[e1 + 1] * q1;
        }
        return pk2(a0, a1, bq0, bq1);
    }
    return 0;
}

// ---- prep: build records, 1 WAVE per patch ----
__global__ __launch_bounds__(64)
void prep_quant(const int* __restrict__ idx,
                const float* __restrict__ W1, const float* __restrict__ b1,
                const float* __restrict__ W2, const float* __restrict__ b2,
                const float* __restrict__ W3, const float* __restrict__ b3,
                const float* __restrict__ wl, uint32_t* __restrict__ ws)
{
    const int p = blockIdx.x;
    const int l = threadIdx.x;           // 0..63
    const float* w1 = W1 + p * 90;
    const float* w2 = W2 + p * 100;
    const float* w3 = W3 + p * 10;

    // wave-parallel amax over W1 (order-independent -> deterministic scale)
    float m1 = (l < 90) ? fabsf(w1[l]) : 0.0f;
    if (l + 64 < 90) m1 = fmaxf(m1, fabsf(w1[l + 64]));
    #pragma unroll
    for (int off = 32; off > 0; off >>= 1)
        m1 = fmaxf(m1, __shfl_xor(m1, off));
    m1 = fmaxf(m1, 1e-20f);
    const float s1 = m1 / F8_MAX, q1 = F8_MAX / m1;

    ws[(size_t)p * REC_DW + l] =
        rec_dword(p, l, idx, w1, b1, w2, b2, w3, b3, wl, s1, q1);
}

__global__ __launch_bounds__(THREADS, 4)
void dnn_q8(const float* __restrict__ x, const uint32_t* __restrict__ ws,
            const float* __restrict__ wl, float* __restrict__ out)
{
    extern __shared__ unsigned char xs[];   // x tile + record slots
    __shared__ float partial[NWAVE][TB];

    const int tid = threadIdx.x;
    const int b0  = blockIdx.x * TB;
    const int p0  = blockIdx.y * PPB;

    // ---- stage x tile (fp32 global, coalesced float4) -> fp8 LDS ----
    #pragma unroll
    for (int i = 0; i < (TB * (F_DIM / 4)) / THREADS; ++i) {   // 32 iters
        const int q   = i * THREADS + tid;
        const int row = q >> 8;
        const int c4  = q & 255;
        const float4 v = *reinterpret_cast<const float4*>(
            x + (size_t)(b0 + row) * F_DIM + (c4 << 2));
        int pk = __builtin_amdgcn_cvt_pk_fp8_f32(v.x, v.y, 0, false);
        pk     = __builtin_amdgcn_cvt_pk_fp8_f32(v.z, v.w, pk, true);
        *reinterpret_cast<uint32_t*>(xs + row * LSTR + (c4 << 2)) = (uint32_t)pk;
    }
    __syncthreads();

    const int lane = tid & 63;
    const int wave = tid >> 6;
    const unsigned char* __restrict__ row0 = xs + lane * LSTR;
    const unsigned char* __restrict__ row1 = xs + (lane + 64) * LSTR;
    // wave-private double-buffered record slots: [NWAVE][2][64] dwords
    uint32_t* slots = reinterpret_cast<uint32_t*>(xs + XS_BYTES) + wave * (2 * REC_DW);

    float y0 = 0.0f, y1 = 0.0f;

    // prologue: stage first record into slot 0 (T14: global -> reg -> LDS)
    slots[lane] = ws[(size_t)(p0 + wave) * REC_DW + lane];
    int cur = 0;

    for (int jp = 0; jp < PPB / NWAVE; ++jp) {   // 32 iters, 1 patch/wave, 2 rows/lane
        const int p = p0 + jp * NWAVE + wave;
        const uint32_t* __restrict__ rec = slots + cur * REC_DW;  // wave-uniform LDS addr
        const float*    __restrict__ rf  = reinterpret_cast<const float*>(rec);

        // T14 issue-early: next record's 256B coalesced load (1 dword/lane);
        // the matching ds_write is ~1800cy later, so latency is fully hidden.
        // Tail reads past record 1023 stay inside ws (>=950KB) - unused.
        const uint32_t stg = ws[(size_t)(p + NWAVE) * REC_DW + lane];

        // gather 9 features for both rows (conflict-free: stride 1028 B)
        float xg0[K_IN], xg1[K_IN];
        #pragma unroll
        for (int k = 0; k < K_IN; ++k) {
            const int c = (int)rec[k];
            xg0[k] = __builtin_amdgcn_cvt_f32_fp8((int)row0[c], 0);
            xg1[k] = __builtin_amdgcn_cvt_f32_fp8((int)row1[c], 0);
        }

        // layer 1: quantized accumulate (W1q via broadcast ds_reads)
        f32x2 H0[5], H1[5];
        #pragma unroll
        for (int j = 0; j < 5; ++j) { H0[j] = f32x2{0.f, 0.f}; H1[j] = f32x2{0.f, 0.f}; }
        #pragma unroll
        for (int k = 0; k < K_IN; ++k) {
            const f32x2 xa = {xg0[k], xg0[k]};
            const f32x2 xb = {xg1[k], xg1[k]};
            #pragma unroll
            for (int j = 0; j < 5; ++j) {
                const int t = k * 5 + j;
                const f32x2 w = unpk8s(rec[32 + (t >> 1)], t & 1);
                H0[j] = pkfma(xa, w, H0[j]);
                H1[j] = pkfma(xb, w, H1[j]);
            }
        }
        // z = H*s1C + b1C; r = 1/(exp2(z)+1)  (tanh = 1-2r folded into cw,c0)
        const float s1c = rf[9];
        const f32x2 s1p = {s1c, s1c};
        f32x2 r0[5], r1[5];
        #pragma unroll
        for (int j = 0; j < 5; ++j) {
            const f32x2 bj = {rf[10 + 2 * j], rf[11 + 2 * j]};
            const f32x2 z0 = pkfma(H0[j], s1p, bj);
            const f32x2 z1 = pkfma(H1[j], s1p, bj);
            r0[j] = f32x2{sigm_r(z0[0]), sigm_r(z0[1])};
            r1[j] = f32x2{sigm_r(z1[0]), sigm_r(z1[1])};
        }

        // collapsed layers 2+3: y += c0 + sum_w cw[w]*r_w
        const float c0 = rf[20];
        f32x2 A0 = {0.f, 0.f}, A1 = {0.f, 0.f};
        #pragma unroll
        for (int j = 0; j < 5; ++j) {
            const f32x2 cwj = {rf[21 + 2 * j], rf[22 + 2 * j]};
            A0 = pkfma(cwj, r0[j], A0);
            A1 = pkfma(cwj, r1[j], A1);
        }
        y0 += c0 + A0[0] + A0[1];
        y1 += c0 + A1[0] + A1[1];

        // T14 write-late: park the prefetched record for the next iteration
        slots[(cur ^ 1) * REC_DW + lane] = stg;
        cur ^= 1;
    }

    partial[wave][lane]      = y0;
    partial[wave][lane + 64] = y1;
    __syncthreads();

    // ---- block reduction over the 16 waves + outputs ----
    if (tid < TB) {
        float s = 0.0f;
        #pragma unroll
        for (int w = 0; w < NWAVE; ++w) s += partial[w][tid];
        // two pgroup blocks contribute per y element; fp32 add is commutative
        atomicAdd(&out[b0 + tid], s);
    }

    if (blockIdx.y == 0 && tid < 64) {
        // channel 2: sum(|w_last|), computed redundantly per row-block
        float sa = 0.0f;
        #pragma unroll
        for (int i = 0; i < P_TOT / 64; ++i) sa += fabsf(wl[tid + 64 * i]);
        #pragma unroll
        for (int off = 32; off > 0; off >>= 1) sa += __shfl_down(sa, off);
        sa = __shfl(sa, 0);
        out[B_TOT + b0 + tid]      = sa;
        out[B_TOT + b0 + 64 + tid] = sa;
    }
}

extern "C" void kernel_launch(void* const* d_in, const int* in_sizes, int n_in,
                              void* d_out, int out_size, void* d_ws, size_t ws_size,
                              hipStream_t stream)
{
    const float* x  = (const float*)d_in[0];
    const int*   idx= (const int*)  d_in[1];
    const float* W1 = (const float*)d_in[2];
    const float* b1 = (const float*)d_in[3];
    const float* W2 = (const float*)d_in[4];
    const float* b2 = (const float*)d_in[5];
    const float* W3 = (const float*)d_in[6];
    const float* b3 = (const float*)d_in[7];
    const float* wl = (const float*)d_in[8];
    float* out = (float*)d_out;
    uint32_t* ws = (uint32_t*)d_ws;   // need 256KB + tail pad; ws >= 950KB (R10)

    // zero the y channel (atomicAdd accumulates into it)
    (void)hipMemsetAsync(out, 0, B_TOT * sizeof(float), stream);

    prep_quant<<<P_TOT, 64, 0, stream>>>(idx, W1, b1, W2, b2, W3, b3, wl, ws);

    const int smem = XS_BYTES + NWAVE * 2 * REC_DW * 4;  // 131584 + 8192 = 139776 B
    (void)hipFuncSetAttribute(reinterpret_cast<const void*>(dnn_q8),
                              hipFuncAttributeMaxDynamicSharedMemorySize, smem);

    dim3 grid(B_TOT / TB, PGRP);   // 128 x 2 = 256 blocks
    dnn_q8<<<grid, THREADS, smem, stream>>>(x, ws, wl, out);
}